// Round 7
// baseline (44.679 us; speedup 1.0000x reference)
//
#include <hip/hip_runtime.h>

#define HH 512
#define WW 512
#define STRIP 32                       // output rows per wave task
#define SPI (HH / STRIP)               // 16 strips per image
#define NTASK (128 * SPI)              // 2048 full-width wave tasks
#define BLOCK 256
#define WPB 4                          // waves per block
#define NBLK (NTASK / WPB)             // 512 blocks -> 2/CU, 8 waves/CU
#define NSLOT (STRIP + 2)              // 34 row slots (rows r0-1 .. r0+32)
#define DEPTH 3                        // prefetch depth (rows in flight)
#define NTOTAL (16.0 * 8.0 * 512.0 * 512.0)
#define SCALE 274877906944.0           // 2^38 fixed-point scale

// Grey opening (2x2 flat SE, scipy origin convention) fused with MSE, single
// dispatch. Body identical to R6 (memory-roofline: 134MB + 6.25% halo at
// ~6.3 TB/s). Tail: per-block partial -> fixed-point u64 device atomicAdd
// (exact, commutative => bit-deterministic) -> last-block-done finalize.
__global__ __launch_bounds__(BLOCK, 2) void opening_fused(
    const float* __restrict__ x, unsigned long long* __restrict__ ws,
    float* __restrict__ out)
{
    // XCD-chunked swizzle (bijective: 512 % 8 == 0): neighbors share an L2.
    const int wb    = (blockIdx.x & 7) * (NBLK / 8) + (blockIdx.x >> 3);
    const int lane  = threadIdx.x & 63;
    const int wid   = wb * WPB + (threadIdx.x >> 6);
    const int img   = wid >> 4;          // / SPI
    const int strip = wid & (SPI - 1);
    const int r0    = strip * STRIP;
    const bool bot  = (strip == SPI - 1);

    const float* ib = x + (size_t)img * (HH * WW);
    const int cA  = lane * 4;
    const int cB  = 256 + lane * 4;
    const int cAm = (lane == 0) ? 0 : cA - 1;      // erosion left clamp
    const int cBm = cB - 1;
    const int cAp = cA + 4;                        // <= 256, always valid
    const int cBp = (cB + 4 > WW - 1) ? (WW - 1) : (cB + 4);
    const bool rcl = (cB + 4 > WW - 1);            // dilation er right clamp

    // slot layout per group: [xm1, x0, x1, x2, x3, x4]
    float RA[NSLOT][6], RB[NSLOT][6];

#define LOADS(s, r)                                                       \
    do {                                                                  \
        const float* rowp = ib + (size_t)(r) * WW;                        \
        const float4 a4 = *(const float4*)(rowp + cA);                    \
        const float4 b4 = *(const float4*)(rowp + cB);                    \
        RA[s][0] = rowp[cAm]; RA[s][1] = a4.x; RA[s][2] = a4.y;           \
        RA[s][3] = a4.z;      RA[s][4] = a4.w; RA[s][5] = rowp[cAp];      \
        RB[s][0] = rowp[cBm]; RB[s][1] = b4.x; RB[s][2] = b4.y;           \
        RB[s][3] = b4.z;      RB[s][4] = b4.w; RB[s][5] = rowp[cBp];      \
    } while (0)

    // column-eroded row: rc[j] = min(x[c+j-1], x[c+j]); rc[9] dilation-clamped
#define RCROW(s, rc)                                                      \
    do {                                                                  \
        rc[0] = fminf(RA[s][0], RA[s][1]); rc[1] = fminf(RA[s][1], RA[s][2]); \
        rc[2] = fminf(RA[s][2], RA[s][3]); rc[3] = fminf(RA[s][3], RA[s][4]); \
        rc[4] = fminf(RA[s][4], RA[s][5]);                                \
        rc[5] = fminf(RB[s][0], RB[s][1]); rc[6] = fminf(RB[s][1], RB[s][2]); \
        rc[7] = fminf(RB[s][2], RB[s][3]); rc[8] = fminf(RB[s][3], RB[s][4]); \
        rc[9] = rcl ? rc[8] : fminf(RB[s][4], RB[s][5]);                  \
    } while (0)

#define CLAMPR(r) (((r) < 0) ? 0 : (((r) > HH - 1) ? (HH - 1) : (r)))

    float rp[10], dp[8];
    float acc = 0.f;

    // prologue: issue first DEPTH rows
#pragma unroll
    for (int s = 0; s < DEPTH; ++s) LOADS(s, CLAMPR(r0 - 1 + s));

    // main: slot s holds x row (r0-1+s); at iter s compute er(r0-1+s),
    // d(r0-1+s), emit op(r0-2+s) for s>=2 (its x lives in slot s-1).
#pragma unroll
    for (int s = 0; s < NSLOT - 1; ++s) {
        if (s + DEPTH < NSLOT) LOADS(s + DEPTH, CLAMPR(r0 - 1 + s + DEPTH));
        float rc[10];
        RCROW(s, rc);
        if (s == 0) {
#pragma unroll
            for (int j = 0; j < 10; ++j) rp[j] = rc[j];
        } else {
            float er[10], d[8];
#pragma unroll
            for (int j = 0; j < 10; ++j) er[j] = fminf(rp[j], rc[j]);
#pragma unroll
            for (int j = 0; j < 4; ++j) {
                d[j]     = fmaxf(er[j], er[j + 1]);          // A cols
                d[4 + j] = fmaxf(er[5 + j], er[6 + j]);      // B cols
            }
            if (s >= 2) {   // emit op(row r0+s-2); its x lives in slot s-1
#pragma unroll
                for (int j = 0; j < 4; ++j) {
                    const float oA = fmaxf(dp[j], d[j]);
                    const float oB = fmaxf(dp[4 + j], d[4 + j]);
                    const float fA = RA[s - 1][j + 1] - oA;
                    const float fB = RB[s - 1][j + 1] - oB;
                    acc = fmaf(fA, fA, acc);
                    acc = fmaf(fB, fB, acc);
                }
            }
#pragma unroll
            for (int j = 0; j < 10; ++j) rp[j] = rc[j];
#pragma unroll
            for (int j = 0; j < 8; ++j) dp[j] = d[j];
        }
    }

    // epilogue (s = NSLOT-1): emit op(row r0+STRIP-1)
    if (!bot) {
        float rc[10], er[10];
        RCROW(NSLOT - 1, rc);
#pragma unroll
        for (int j = 0; j < 10; ++j) er[j] = fminf(rp[j], rc[j]);
#pragma unroll
        for (int j = 0; j < 4; ++j) {
            const float dA = fmaxf(er[j], er[j + 1]);
            const float dB = fmaxf(er[5 + j], er[6 + j]);
            const float fA = RA[NSLOT - 2][j + 1] - fmaxf(dp[j], dA);
            const float fB = RB[NSLOT - 2][j + 1] - fmaxf(dp[4 + j], dB);
            acc = fmaf(fA, fA, acc);
            acc = fmaf(fB, fB, acc);
        }
    } else {
        // image bottom: row clamp => op(H-1) = d(H-1) = dp
#pragma unroll
        for (int j = 0; j < 4; ++j) {
            const float fA = RA[NSLOT - 2][j + 1] - dp[j];
            const float fB = RB[NSLOT - 2][j + 1] - dp[4 + j];
            acc = fmaf(fA, fA, acc);
            acc = fmaf(fB, fB, acc);
        }
    }
#undef LOADS
#undef RCROW
#undef CLAMPR

    // deterministic block partial: wave shfl tree -> LDS -> fixed-order sum
    __shared__ float wsum[WPB];
#pragma unroll
    for (int off = 32; off; off >>= 1) acc += __shfl_down(acc, off);
    if (lane == 0) wsum[threadIdx.x >> 6] = acc;
    __syncthreads();

    // fused finalize: fixed-point u64 atomics (exact => deterministic).
    // ws[0] = sum (units of 2^-38), ws[1] = completion counter.
    if (threadIdx.x == 0) {
        const double p = (double)((wsum[0] + wsum[1]) + (wsum[2] + wsum[3]));
        const unsigned long long q = (unsigned long long)(p * SCALE + 0.5);
        atomicAdd(&ws[0], q);
        __threadfence();                         // publish sum before counter
        const unsigned long long old = atomicAdd(&ws[1], 1ULL);
        if (old == (unsigned long long)(NBLK - 1)) {
            // all 512 sum-adds are ordered before their counter increments
            const unsigned long long tot = atomicAdd(&ws[0], 0ULL);  // coherent read
            out[0] = (float)((double)tot / SCALE / NTOTAL);
        }
    }
}

extern "C" void kernel_launch(void* const* d_in, const int* in_sizes, int n_in,
                              void* d_out, int out_size, void* d_ws, size_t ws_size,
                              hipStream_t stream)
{
    const float* x = (const float*)d_in[0];
    unsigned long long* ws = (unsigned long long*)d_ws;  // [sum, counter]
    float* out = (float*)d_out;

    hipMemsetAsync(ws, 0, 2 * sizeof(unsigned long long), stream);
    opening_fused<<<NBLK, BLOCK, 0, stream>>>(x, ws, out);
}

// Round 8
// 27.282 us; speedup vs baseline: 1.6376x; 1.6376x over previous
//
#include <hip/hip_runtime.h>

#define HH 512
#define WW 512
#define STRIP 32                       // output rows per wave task
#define SPI (HH / STRIP)               // 16 strips per image
#define NTASK (128 * SPI)              // 2048 full-width wave tasks
#define BLOCK 256
#define WPB 4                          // waves per block
#define NBLK (NTASK / WPB)             // 512 blocks -> 2/CU, 8 waves/CU
#define NSLOT (STRIP + 2)              // 34 row slots (rows r0-1 .. r0+32)
#define DEPTH 3                        // prefetch depth (rows in flight)
#define NTOTAL (16.0 * 8.0 * 512.0 * 512.0)

// Grey opening (2x2 flat SE, scipy origin convention) fused with MSE partials.
// Memory-roofline design: input is 134 MB; halo overhead = 2/STRIP = 6.25%.
// Lane owns cols [4i,4i+4) (A) and [256+4i,256+4i+4) (B): each per-row float4
// is part of a fully-contiguous 1KB wave access; the 4 halo dwords hit lines
// the same wave just fetched (L1). Zero cross-lane ops; pure per-lane
// dataflow; depth-3 rolling prefetch with statically-indexed slots.
// NOTE (R7 lesson): this unrolled body's regalloc is fragile — adding f64/u64
// atomic tail code to this kernel collapsed it to 52 VGPR + scratch spill
// (44.7 us total). Keep the tail a plain LDS reduce + store; reduce elsewhere.
__global__ __launch_bounds__(BLOCK, 2) void opening_partial(
    const float* __restrict__ x, float* __restrict__ partial)
{
    // XCD-chunked swizzle (bijective: 512 % 8 == 0): neighbors share an L2.
    const int wb    = (blockIdx.x & 7) * (NBLK / 8) + (blockIdx.x >> 3);
    const int lane  = threadIdx.x & 63;
    const int wid   = wb * WPB + (threadIdx.x >> 6);
    const int img   = wid >> 4;          // / SPI
    const int strip = wid & (SPI - 1);
    const int r0    = strip * STRIP;
    const bool bot  = (strip == SPI - 1);

    const float* ib = x + (size_t)img * (HH * WW);
    const int cA  = lane * 4;
    const int cB  = 256 + lane * 4;
    const int cAm = (lane == 0) ? 0 : cA - 1;      // erosion left clamp
    const int cBm = cB - 1;
    const int cAp = cA + 4;                        // <= 256, always valid
    const int cBp = (cB + 4 > WW - 1) ? (WW - 1) : (cB + 4);
    const bool rcl = (cB + 4 > WW - 1);            // dilation er right clamp

    // slot layout per group: [xm1, x0, x1, x2, x3, x4]
    float RA[NSLOT][6], RB[NSLOT][6];

#define LOADS(s, r)                                                       \
    do {                                                                  \
        const float* rowp = ib + (size_t)(r) * WW;                        \
        const float4 a4 = *(const float4*)(rowp + cA);                    \
        const float4 b4 = *(const float4*)(rowp + cB);                    \
        RA[s][0] = rowp[cAm]; RA[s][1] = a4.x; RA[s][2] = a4.y;           \
        RA[s][3] = a4.z;      RA[s][4] = a4.w; RA[s][5] = rowp[cAp];      \
        RB[s][0] = rowp[cBm]; RB[s][1] = b4.x; RB[s][2] = b4.y;           \
        RB[s][3] = b4.z;      RB[s][4] = b4.w; RB[s][5] = rowp[cBp];      \
    } while (0)

    // column-eroded row: rc[j] = min(x[c+j-1], x[c+j]); rc[9] dilation-clamped
#define RCROW(s, rc)                                                      \
    do {                                                                  \
        rc[0] = fminf(RA[s][0], RA[s][1]); rc[1] = fminf(RA[s][1], RA[s][2]); \
        rc[2] = fminf(RA[s][2], RA[s][3]); rc[3] = fminf(RA[s][3], RA[s][4]); \
        rc[4] = fminf(RA[s][4], RA[s][5]);                                \
        rc[5] = fminf(RB[s][0], RB[s][1]); rc[6] = fminf(RB[s][1], RB[s][2]); \
        rc[7] = fminf(RB[s][2], RB[s][3]); rc[8] = fminf(RB[s][3], RB[s][4]); \
        rc[9] = rcl ? rc[8] : fminf(RB[s][4], RB[s][5]);                  \
    } while (0)

#define CLAMPR(r) (((r) < 0) ? 0 : (((r) > HH - 1) ? (HH - 1) : (r)))

    float rp[10], dp[8];
    float acc = 0.f;

    // prologue: issue first DEPTH rows
#pragma unroll
    for (int s = 0; s < DEPTH; ++s) LOADS(s, CLAMPR(r0 - 1 + s));

    // main: slot s holds x row (r0-1+s); at iter s compute er(r0-1+s),
    // d(r0-1+s), emit op(r0-2+s) for s>=2 (its x lives in slot s-1).
#pragma unroll
    for (int s = 0; s < NSLOT - 1; ++s) {
        if (s + DEPTH < NSLOT) LOADS(s + DEPTH, CLAMPR(r0 - 1 + s + DEPTH));
        float rc[10];
        RCROW(s, rc);
        if (s == 0) {
#pragma unroll
            for (int j = 0; j < 10; ++j) rp[j] = rc[j];
        } else {
            float er[10], d[8];
#pragma unroll
            for (int j = 0; j < 10; ++j) er[j] = fminf(rp[j], rc[j]);
#pragma unroll
            for (int j = 0; j < 4; ++j) {
                d[j]     = fmaxf(er[j], er[j + 1]);          // A cols
                d[4 + j] = fmaxf(er[5 + j], er[6 + j]);      // B cols
            }
            if (s >= 2) {   // emit op(row r0+s-2); its x lives in slot s-1
#pragma unroll
                for (int j = 0; j < 4; ++j) {
                    const float oA = fmaxf(dp[j], d[j]);
                    const float oB = fmaxf(dp[4 + j], d[4 + j]);
                    const float fA = RA[s - 1][j + 1] - oA;
                    const float fB = RB[s - 1][j + 1] - oB;
                    acc = fmaf(fA, fA, acc);
                    acc = fmaf(fB, fB, acc);
                }
            }
#pragma unroll
            for (int j = 0; j < 10; ++j) rp[j] = rc[j];
#pragma unroll
            for (int j = 0; j < 8; ++j) dp[j] = d[j];
        }
    }

    // epilogue (s = NSLOT-1): emit op(row r0+STRIP-1)
    if (!bot) {
        float rc[10], er[10];
        RCROW(NSLOT - 1, rc);
#pragma unroll
        for (int j = 0; j < 10; ++j) er[j] = fminf(rp[j], rc[j]);
#pragma unroll
        for (int j = 0; j < 4; ++j) {
            const float dA = fmaxf(er[j], er[j + 1]);
            const float dB = fmaxf(er[5 + j], er[6 + j]);
            const float fA = RA[NSLOT - 2][j + 1] - fmaxf(dp[j], dA);
            const float fB = RB[NSLOT - 2][j + 1] - fmaxf(dp[4 + j], dB);
            acc = fmaf(fA, fA, acc);
            acc = fmaf(fB, fB, acc);
        }
    } else {
        // image bottom: row clamp => op(H-1) = d(H-1) = dp
#pragma unroll
        for (int j = 0; j < 4; ++j) {
            const float fA = RA[NSLOT - 2][j + 1] - dp[j];
            const float fB = RB[NSLOT - 2][j + 1] - dp[4 + j];
            acc = fmaf(fA, fA, acc);
            acc = fmaf(fB, fB, acc);
        }
    }
#undef LOADS
#undef RCROW
#undef CLAMPR

    // deterministic block partial: wave shfl tree -> LDS -> fixed-order sum
    __shared__ float wsum[WPB];
#pragma unroll
    for (int off = 32; off; off >>= 1) acc += __shfl_down(acc, off);
    if (lane == 0) wsum[threadIdx.x >> 6] = acc;
    __syncthreads();
    if (threadIdx.x == 0)
        partial[blockIdx.x] = (wsum[0] + wsum[1]) + (wsum[2] + wsum[3]);
}

// Deterministic final reduction: 512 partials, ONE WAVE, no LDS, no barrier.
// Fixed lane assignment + fixed shfl tree order => bit-stable across replays.
__global__ __launch_bounds__(64) void reduce_final(
    const float* __restrict__ partial, float* __restrict__ out)
{
    const int t = threadIdx.x;
    double s = 0.0;
#pragma unroll
    for (int i = 0; i < NBLK / 64; ++i) s += (double)partial[t + 64 * i];
#pragma unroll
    for (int off = 32; off; off >>= 1) s += __shfl_down(s, off);
    if (t == 0) out[0] = (float)(s / NTOTAL);
}

extern "C" void kernel_launch(void* const* d_in, const int* in_sizes, int n_in,
                              void* d_out, int out_size, void* d_ws, size_t ws_size,
                              hipStream_t stream)
{
    const float* x = (const float*)d_in[0];
    float* partial = (float*)d_ws;     // NBLK floats = 2 KB scratch
    float* out = (float*)d_out;

    opening_partial<<<NBLK, BLOCK, 0, stream>>>(x, partial);
    reduce_final<<<1, 64, 0, stream>>>(partial, out);
}